// Round 4
// baseline (315.378 us; speedup 1.0000x reference)
//
#include <hip/hip_runtime.h>
#include <hip/hip_bf16.h>

#define BB 64
#define TT 1024
#define AA 128
#define FF 1024
#define DQ 1024
#define DV 512

typedef __bf16 bf16x8_t __attribute__((ext_vector_type(8)));
typedef __bf16 bf16x4_t __attribute__((ext_vector_type(4)));
typedef float f32x4_t __attribute__((ext_vector_type(4)));
typedef _Float16 f16x4_t __attribute__((ext_vector_type(4)));

__device__ __forceinline__ float ftanh(float x) {
    float e = __expf(2.0f * x);
    return 1.0f - 2.0f / (e + 1.0f);
}

__device__ __forceinline__ __bf16 bhi(float x) { return (__bf16)x; }
__device__ __forceinline__ __bf16 blo(float x) {
    __bf16 h = (__bf16)x;
    return (__bf16)(x - (float)h);
}

// ---------------- K_prep ----------------
// blocks 0..15:  Wm slab s (32 d) -> packed pwm hi/lo, fragment order
//                P[((s*8+g)*64 + lane)*8 + j] = Wm[s*32 + (lane>>4)*8 + j][g*16 + (lane&15)]
// blocks 16..23: Wconv -> wct[f][64] hi/lo (kc padded to 64)
// blocks 24..55: Wloc slab s2 (32 t) -> packed pwl hi/lo, same fragment order over t
// blocks 56..119: query GEMM (1 b each)
__global__ __launch_bounds__(256) void k_prep(
    const float* __restrict__ Wm, const float* __restrict__ Wconv,
    const float* __restrict__ Wloc, const float* __restrict__ query,
    const float* __restrict__ Wq,
    __bf16* __restrict__ pwmhi, __bf16* __restrict__ pwmlo,
    __bf16* __restrict__ wcthi, __bf16* __restrict__ wctlo,
    __bf16* __restrict__ pwlhi, __bf16* __restrict__ pwllo,
    float* __restrict__ q_ws) {
    __shared__ float ls[128 * 65];
    int bx = blockIdx.x, tid = threadIdx.x;
    if (bx < 16) {
        int s = bx, d0 = s * 32;
        for (int i = tid; i < 4096; i += 256) {
            int dd = i >> 7, a = i & 127;
            ls[a * 33 + dd] = Wm[(d0 + dd) * AA + a];
        }
        __syncthreads();
#pragma unroll
        for (int u = 0; u < 2; u++) {
            int pos = tid * 2 + u;                 // 0..511
            int l15 = pos & 15, lq = (pos >> 4) & 3, g = pos >> 6;
            bf16x8_t h8, l8;
#pragma unroll
            for (int j = 0; j < 8; j++) {
                float x = ls[(g * 16 + l15) * 33 + lq * 8 + j];
                h8[j] = bhi(x);
                l8[j] = blo(x);
            }
            size_t off = (size_t)(s * 512 + pos) * 8;
            *(bf16x8_t*)(pwmhi + off) = h8;
            *(bf16x8_t*)(pwmlo + off) = l8;
        }
    } else if (bx < 24) {
        int f0 = (bx - 16) * 128;
        for (int i = tid; i < 8192; i += 256) {
            int kc = i >> 7, f = i & 127;
            ls[f * 65 + kc] = (kc < 62) ? Wconv[kc * FF + f0 + f] : 0.f;
        }
        __syncthreads();
        int f = tid >> 1, half = tid & 1;
#pragma unroll
        for (int g = 0; g < 4; g++) {
            bf16x8_t h8, l8;
#pragma unroll
            for (int j = 0; j < 8; j++) {
                float x = ls[f * 65 + half * 32 + g * 8 + j];
                h8[j] = bhi(x);
                l8[j] = blo(x);
            }
            size_t off = (size_t)(f0 + f) * 64 + half * 32 + g * 8;
            *(bf16x8_t*)(wcthi + off) = h8;
            *(bf16x8_t*)(wctlo + off) = l8;
        }
    } else if (bx < 56) {
        int s2 = bx - 24, t0 = s2 * 32;
        for (int i = tid; i < 4096; i += 256) {
            int tt = i >> 7, a = i & 127;
            ls[a * 33 + tt] = Wloc[(t0 + tt) * AA + a];
        }
        __syncthreads();
#pragma unroll
        for (int u = 0; u < 2; u++) {
            int pos = tid * 2 + u;
            int l15 = pos & 15, lq = (pos >> 4) & 3, g = pos >> 6;
            bf16x8_t h8, l8;
#pragma unroll
            for (int j = 0; j < 8; j++) {
                float x = ls[(g * 16 + l15) * 33 + lq * 8 + j];
                h8[j] = bhi(x);
                l8[j] = blo(x);
            }
            size_t off = (size_t)(s2 * 512 + pos) * 8;
            *(bf16x8_t*)(pwlhi + off) = h8;
            *(bf16x8_t*)(pwllo + off) = l8;
        }
    } else {
        int b = bx - 56;
        int a = tid & 127, half = tid >> 7;
        const float* qrow = query + b * DQ + half * 512;
        float a0 = 0.f, a1 = 0.f, a2 = 0.f, a3 = 0.f;
        for (int d = 0; d < 512; d += 4) {
            float4 qv = *(const float4*)(qrow + d);
            int dg = (half * 512 + d) * AA + a;
            a0 += qv.x * Wq[dg];
            a1 += qv.y * Wq[dg + AA];
            a2 += qv.z * Wq[dg + 2 * AA];
            a3 += qv.w * Wq[dg + 3 * AA];
        }
        ls[tid] = a0 + a1 + a2 + a3;
        __syncthreads();
        if (half == 0) q_ws[b * AA + a] = ftanh(ls[a] + ls[a + 128]);
    }
}

// ---------------- K_zq: z[b][kc][a] = sum_t X[kc][t]*Wloc[t][a] via MFMA ----------------
// B frags from packed pwl (coalesced). Output transposed bf16 hi/lo [b][a][64].
__global__ __launch_bounds__(256) void k_zq(
    const float* __restrict__ xcat,
    const __bf16* __restrict__ pwlhi, const __bf16* __restrict__ pwllo,
    __bf16* __restrict__ zthi, __bf16* __restrict__ ztlo) {
    int b = blockIdx.x, tid = threadIdx.x;
    __shared__ float xs0[1056], xs1[1056];
    __shared__ float zs[64 * 132];
    for (int i = tid; i < 1056; i += 256) {
        int t = i - 16;
        float2 xv = (t >= 0 && t < TT) ? *(const float2*)(xcat + (size_t)(b * TT + t) * 2)
                                       : make_float2(0.f, 0.f);
        xs0[i] = xv.x;
        xs1[i] = xv.y;
    }
    __syncthreads();
    int lane = tid & 63, wid = tid >> 6;
    int wm = wid >> 1, wn = wid & 1;
    int l15 = lane & 15, lq = lane >> 4;

    f32x4_t zacc[2][4];
#pragma unroll
    for (int mi = 0; mi < 2; mi++)
#pragma unroll
        for (int ni = 0; ni < 4; ni++) zacc[mi][ni] = (f32x4_t){0.f, 0.f, 0.f, 0.f};

    for (int s = 0; s < 32; s++) {
        int t0 = s * 32;
        bf16x8_t bh[4], bl[4];
#pragma unroll
        for (int ni = 0; ni < 4; ni++) {
            size_t poff = (size_t)((s * 8 + wn * 4 + ni) * 64 + lane) * 8;
            bh[ni] = *(const bf16x8_t*)(pwlhi + poff);
            bl[ni] = *(const bf16x8_t*)(pwllo + poff);
        }
        bf16x8_t ah[2], al[2];
#pragma unroll
        for (int mi = 0; mi < 2; mi++) {
            int kc = wm * 32 + mi * 16 + l15;
            const float* xsc = (kc & 1) ? xs1 : xs0;
            int base = t0 + lq * 8 + (kc >> 1) + 1;
#pragma unroll
            for (int j = 0; j < 8; j++) {
                float x = xsc[base + j];
                ah[mi][j] = bhi(x);
                al[mi][j] = blo(x);
            }
        }
#pragma unroll
        for (int ni = 0; ni < 4; ni++)
#pragma unroll
            for (int mi = 0; mi < 2; mi++) {
                zacc[mi][ni] = __builtin_amdgcn_mfma_f32_16x16x32_bf16(ah[mi], bh[ni], zacc[mi][ni], 0, 0, 0);
                zacc[mi][ni] = __builtin_amdgcn_mfma_f32_16x16x32_bf16(al[mi], bh[ni], zacc[mi][ni], 0, 0, 0);
                zacc[mi][ni] = __builtin_amdgcn_mfma_f32_16x16x32_bf16(ah[mi], bl[ni], zacc[mi][ni], 0, 0, 0);
            }
    }
#pragma unroll
    for (int mi = 0; mi < 2; mi++)
#pragma unroll
        for (int ni = 0; ni < 4; ni++)
#pragma unroll
            for (int r = 0; r < 4; r++)
                zs[(wm * 32 + mi * 16 + lq * 4 + r) * 132 + wn * 64 + ni * 16 + l15] = zacc[mi][ni][r];
    __syncthreads();
    int a = tid >> 1, half = tid & 1;
#pragma unroll
    for (int g = 0; g < 4; g++) {
        bf16x8_t h8, l8;
#pragma unroll
        for (int j = 0; j < 8; j++) {
            float x = zs[(half * 32 + g * 8 + j) * 132 + a];
            h8[j] = bhi(x);
            l8[j] = blo(x);
        }
        size_t off = ((size_t)b * AA + a) * 64 + half * 32 + g * 8;
        *(bf16x8_t*)(zthi + off) = h8;
        *(bf16x8_t*)(ztlo + off) = l8;
    }
}

// ---------------- K_main: v = tanh(value@Wm), loc = tanh(wct@z), fused score ----------------
// Barrier-free: A fragments loaded directly from global (8 consecutive d = 32B contiguous),
// converted to bf16 hi/lo in registers. No LDS staging. 64 t-rows x 128 a per block;
// 1024 blocks (4/CU); 4 waves (2 wm x 2 wn), each 32x64. Register double-buffer A (HBM/L3)
// and B (L2-resident pwm) one iteration deep, ENFORCED by a memory-clobber fence between
// the prefetch-issue block and the consume block (otherwise regalloc sinks the loads to
// their uses — round-2 showed VGPR=68, i.e. no live buffers, fully latency-exposed).
__global__ __launch_bounds__(256, 3) void k_main(
    const float* __restrict__ value,
    const __bf16* __restrict__ pwmhi, const __bf16* __restrict__ pwmlo,
    const __bf16* __restrict__ wcthi, const __bf16* __restrict__ wctlo,
    const __bf16* __restrict__ zthi, const __bf16* __restrict__ ztlo,
    const float* __restrict__ q_ws, const float* __restrict__ Wv,
    _Float16* __restrict__ v_ws, float* __restrict__ score) {
    int b = blockIdx.x >> 4;
    int trow0 = (blockIdx.x & 15) << 6;
    int tid = threadIdx.x;
    int lane = tid & 63, wid = tid >> 6;
    int wm = wid >> 1, wn = wid & 1;
    int l15 = lane & 15, lq = lane >> 4;

    __shared__ float sc_red[128];

    f32x4_t acc[2][4];
#pragma unroll
    for (int mi = 0; mi < 2; mi++)
#pragma unroll
        for (int ni = 0; ni < 4; ni++) acc[mi][ni] = (f32x4_t){0.f, 0.f, 0.f, 0.f};

    // per-lane A row pointers: row t = trow0 + wm*32 + mi*16 + l15, k-offset lq*8
    const float* arow0 = value + (size_t)(b * TT + trow0 + wm * 32 + l15) * DV + lq * 8;
    const float* arow1 = arow0 + (size_t)16 * DV;

    f32x4_t fa[2][2][2];    // [buf][mi][half-of-8-floats]
    bf16x8_t bhb[2][4], blb[2][4];

    // preload it = 0
#pragma unroll
    for (int h = 0; h < 2; h++) {
        fa[0][0][h] = *(const f32x4_t*)(arow0 + h * 4);
        fa[0][1][h] = *(const f32x4_t*)(arow1 + h * 4);
    }
#pragma unroll
    for (int ni = 0; ni < 4; ni++) {
        size_t poff = (size_t)((wn * 4 + ni) * 64 + lane) * 8;
        bhb[0][ni] = *(const bf16x8_t*)(pwmhi + poff);
        blb[0][ni] = *(const bf16x8_t*)(pwmlo + poff);
    }

#pragma unroll
    for (int it = 0; it < 16; ++it) {
        int cur = it & 1, nxt = cur ^ 1;
        if (it < 15) {
            int d = (it + 1) * 32;
#pragma unroll
            for (int h = 0; h < 2; h++) {
                fa[nxt][0][h] = *(const f32x4_t*)(arow0 + d + h * 4);
                fa[nxt][1][h] = *(const f32x4_t*)(arow1 + d + h * 4);
            }
#pragma unroll
            for (int ni = 0; ni < 4; ni++) {
                size_t poff = (size_t)(((it + 1) * 8 + wn * 4 + ni) * 64 + lane) * 8;
                bhb[nxt][ni] = *(const bf16x8_t*)(pwmhi + poff);
                blb[nxt][ni] = *(const bf16x8_t*)(pwmlo + poff);
            }
        }
        // Pin the pipeline: loads above may not sink below this point; consume code may
        // not hoist above it. Forces prefetch results to stay live (true double-buffer,
        // counted vmcnt instead of per-use drain).
        asm volatile("" ::: "memory");
        bf16x8_t ah[2], al[2];
#pragma unroll
        for (int mi = 0; mi < 2; mi++)
#pragma unroll
            for (int h = 0; h < 2; h++)
#pragma unroll
                for (int j = 0; j < 4; j++) {
                    float x = fa[cur][mi][h][j];
                    ah[mi][h * 4 + j] = bhi(x);
                    al[mi][h * 4 + j] = blo(x);
                }
#pragma unroll
        for (int mi = 0; mi < 2; mi++)
#pragma unroll
            for (int ni = 0; ni < 4; ni++) {
                acc[mi][ni] = __builtin_amdgcn_mfma_f32_16x16x32_bf16(ah[mi], bhb[cur][ni], acc[mi][ni], 0, 0, 0);
                acc[mi][ni] = __builtin_amdgcn_mfma_f32_16x16x32_bf16(al[mi], bhb[cur][ni], acc[mi][ni], 0, 0, 0);
                acc[mi][ni] = __builtin_amdgcn_mfma_f32_16x16x32_bf16(ah[mi], blb[cur][ni], acc[mi][ni], 0, 0, 0);
            }
    }

    // ---- loc gemm: K=64, kc 62/63 zero-padded in wct ----
    f32x4_t lacc[2][4];
#pragma unroll
    for (int mi = 0; mi < 2; mi++)
#pragma unroll
        for (int ni = 0; ni < 4; ni++) lacc[mi][ni] = (f32x4_t){0.f, 0.f, 0.f, 0.f};
#pragma unroll
    for (int kc0 = 0; kc0 < 64; kc0 += 32) {
        bf16x8_t a2h[2], a2l[2], b2h[4], b2l[4];
#pragma unroll
        for (int mi = 0; mi < 2; mi++) {
            int f = trow0 + wm * 32 + mi * 16 + l15;
            a2h[mi] = *(const bf16x8_t*)(wcthi + (size_t)f * 64 + kc0 + lq * 8);
            a2l[mi] = *(const bf16x8_t*)(wctlo + (size_t)f * 64 + kc0 + lq * 8);
        }
#pragma unroll
        for (int ni = 0; ni < 4; ni++) {
            int a = wn * 64 + ni * 16 + l15;
            size_t off = ((size_t)b * AA + a) * 64 + kc0 + lq * 8;
            b2h[ni] = *(const bf16x8_t*)(zthi + off);
            b2l[ni] = *(const bf16x8_t*)(ztlo + off);
        }
#pragma unroll
        for (int mi = 0; mi < 2; mi++)
#pragma unroll
            for (int ni = 0; ni < 4; ni++) {
                lacc[mi][ni] = __builtin_amdgcn_mfma_f32_16x16x32_bf16(a2h[mi], b2h[ni], lacc[mi][ni], 0, 0, 0);
                lacc[mi][ni] = __builtin_amdgcn_mfma_f32_16x16x32_bf16(a2l[mi], b2h[ni], lacc[mi][ni], 0, 0, 0);
                lacc[mi][ni] = __builtin_amdgcn_mfma_f32_16x16x32_bf16(a2h[mi], b2l[ni], lacc[mi][ni], 0, 0, 0);
            }
    }

    // ---- epilogue ----
    float qv[4], wv[4];
#pragma unroll
    for (int ni = 0; ni < 4; ni++) {
        int a = wn * 64 + ni * 16 + l15;
        qv[ni] = q_ws[b * AA + a];
        wv[ni] = Wv[a];
    }
#pragma unroll
    for (int mi = 0; mi < 2; mi++) {
#pragma unroll
        for (int r = 0; r < 4; r++) {
            int tl = wm * 32 + mi * 16 + lq * 4 + r;
            int t = trow0 + tl;
            float s = 0.f;
#pragma unroll
            for (int ni = 0; ni < 4; ni++) {
                float v = ftanh(acc[mi][ni][r]);
                float loc = ftanh(lacc[mi][ni][r]);
                int a = wn * 64 + ni * 16 + l15;
                v_ws[(size_t)(b * TT + t) * AA + a] = (_Float16)v;
                s += ftanh(qv[ni] + v + loc) * wv[ni];
            }
            s += __shfl_xor(s, 1, 64);
            s += __shfl_xor(s, 2, 64);
            s += __shfl_xor(s, 4, 64);
            s += __shfl_xor(s, 8, 64);
            if (l15 == 0) sc_red[wn * 64 + tl] = s;
        }
    }
    __syncthreads();
    if (tid < 64) score[b * TT + trow0 + tid] = sc_red[tid] + sc_red[64 + tid];
}

// ---------------- K_softmax ----------------
__global__ void k_softmax(const float* __restrict__ score, float* __restrict__ out_align) {
    int b = blockIdx.x, tid = threadIdx.x;
    __shared__ float red[4];
    float s[4];
#pragma unroll
    for (int i = 0; i < 4; i++) s[i] = score[b * TT + tid + i * 256];
    float m = fmaxf(fmaxf(s[0], s[1]), fmaxf(s[2], s[3]));
    for (int off = 32; off; off >>= 1) m = fmaxf(m, __shfl_xor(m, off, 64));
    int wid = tid >> 6;
    if ((tid & 63) == 0) red[wid] = m;
    __syncthreads();
    float M = fmaxf(fmaxf(red[0], red[1]), fmaxf(red[2], red[3]));
    __syncthreads();
    float e[4];
    float sum = 0.f;
#pragma unroll
    for (int i = 0; i < 4; i++) { e[i] = __expf(s[i] - M); sum += e[i]; }
    for (int off = 32; off; off >>= 1) sum += __shfl_xor(sum, off, 64);
    if ((tid & 63) == 0) red[wid] = sum;
    __syncthreads();
    float inv = 1.0f / (red[0] + red[1] + red[2] + red[3]);
#pragma unroll
    for (int i = 0; i < 4; i++) out_align[b * TT + tid + i * 256] = e[i] * inv;
}

// ---------------- K_context: context[b,a] = sum_t align[b,t] * v[b,t,a] (v in f16) ----------------
__global__ void k_context(const float* __restrict__ align, const _Float16* __restrict__ v_ws,
                          float* __restrict__ out_ctx) {
    int b = blockIdx.y, t0 = blockIdx.x * 64, tid = threadIdx.x;
    int a0 = (tid & 31) * 4, tl = tid >> 5;
    __shared__ float sh[8 * 132];
    f32x4_t acc = (f32x4_t){0.f, 0.f, 0.f, 0.f};
    for (int tt = tl; tt < 64; tt += 8) {
        float w = align[b * TT + t0 + tt];
        f16x4_t vv = *(const f16x4_t*)(v_ws + (size_t)(b * TT + t0 + tt) * AA + a0);
        acc[0] += w * (float)vv[0];
        acc[1] += w * (float)vv[1];
        acc[2] += w * (float)vv[2];
        acc[3] += w * (float)vv[3];
    }
    *(f32x4_t*)&sh[tl * 132 + a0] = acc;
    __syncthreads();
    if (tid < 128) {
        float s = 0.f;
#pragma unroll
        for (int j = 0; j < 8; j++) s += sh[j * 132 + tid];
        atomicAdd(out_ctx + b * AA + tid, s);
    }
}

extern "C" void kernel_launch(void* const* d_in, const int* in_sizes, int n_in,
                              void* d_out, int out_size, void* d_ws, size_t ws_size,
                              hipStream_t stream) {
    const float* query = (const float*)d_in[0];
    const float* value = (const float*)d_in[1];
    const float* xcat  = (const float*)d_in[2];
    const float* Wq    = (const float*)d_in[3];
    const float* Wm    = (const float*)d_in[4];
    const float* Wv    = (const float*)d_in[5];
    const float* Wconv = (const float*)d_in[6];
    const float* Wloc  = (const float*)d_in[7];
    float* out = (float*)d_out;

    float* ws = (float*)d_ws;
    float* q_ws  = ws;                       // 8192
    float* sc_ws = q_ws + 8192;              // 65536
    _Float16* v_ws = (_Float16*)(sc_ws + 65536);  // 8388608 halfs = 4194304 floats
    __bf16* pwmhi = (__bf16*)(sc_ws + 65536 + 4194304);
    __bf16* pwmlo = pwmhi + 65536;
    __bf16* wcthi = pwmlo + 65536;
    __bf16* wctlo = wcthi + 65536;
    __bf16* pwlhi = wctlo + 65536;           // 131072
    __bf16* pwllo = pwlhi + 131072;
    __bf16* zthi  = pwllo + 131072;          // 524288
    __bf16* ztlo  = zthi + 524288;

    (void)hipMemsetAsync(out, 0, (size_t)8192 * 4, stream);  // context accumulated via atomics

    k_prep<<<120, 256, 0, stream>>>(Wm, Wconv, Wloc, query, Wq,
                                    pwmhi, pwmlo, wcthi, wctlo, pwlhi, pwllo, q_ws);
    k_zq<<<BB, 256, 0, stream>>>(xcat, pwlhi, pwllo, zthi, ztlo);
    k_main<<<1024, 256, 0, stream>>>(value, pwmhi, pwmlo, wcthi, wctlo, zthi, ztlo,
                                     q_ws, Wv, v_ws, sc_ws);
    k_softmax<<<BB, 256, 0, stream>>>(sc_ws, out + 8192);
    k_context<<<dim3(16, BB), 256, 0, stream>>>(out + 8192, v_ws, out);
}

// Round 5
// 304.684 us; speedup vs baseline: 1.0351x; 1.0351x over previous
//
#include <hip/hip_runtime.h>
#include <hip/hip_bf16.h>

#define BB 64
#define TT 1024
#define AA 128
#define FF 1024
#define DQ 1024
#define DV 512

typedef __bf16 bf16x8_t __attribute__((ext_vector_type(8)));
typedef __bf16 bf16x4_t __attribute__((ext_vector_type(4)));
typedef float f32x4_t __attribute__((ext_vector_type(4)));
typedef _Float16 f16x4_t __attribute__((ext_vector_type(4)));

__device__ __forceinline__ float ftanh(float x) {
    float e = __expf(2.0f * x);
    return 1.0f - 2.0f / (e + 1.0f);
}

__device__ __forceinline__ __bf16 bhi(float x) { return (__bf16)x; }
__device__ __forceinline__ __bf16 blo(float x) {
    __bf16 h = (__bf16)x;
    return (__bf16)(x - (float)h);
}

// ---------------- K_prep ----------------
// blocks 0..15:  Wm slab s (32 d) -> packed pwm hi/lo, fragment order
//                P[((s*8+g)*64 + lane)*8 + j] = Wm[s*32 + (lane>>4)*8 + j][g*16 + (lane&15)]
// blocks 16..23: Wconv -> wct[f][64] hi/lo (kc padded to 64)
// blocks 24..55: Wloc slab s2 (32 t) -> packed pwl hi/lo, same fragment order over t
// blocks 56..119: query GEMM (1 b each)
__global__ __launch_bounds__(256) void k_prep(
    const float* __restrict__ Wm, const float* __restrict__ Wconv,
    const float* __restrict__ Wloc, const float* __restrict__ query,
    const float* __restrict__ Wq,
    __bf16* __restrict__ pwmhi, __bf16* __restrict__ pwmlo,
    __bf16* __restrict__ wcthi, __bf16* __restrict__ wctlo,
    __bf16* __restrict__ pwlhi, __bf16* __restrict__ pwllo,
    float* __restrict__ q_ws) {
    __shared__ float ls[128 * 65];
    int bx = blockIdx.x, tid = threadIdx.x;
    if (bx < 16) {
        int s = bx, d0 = s * 32;
        for (int i = tid; i < 4096; i += 256) {
            int dd = i >> 7, a = i & 127;
            ls[a * 33 + dd] = Wm[(d0 + dd) * AA + a];
        }
        __syncthreads();
#pragma unroll
        for (int u = 0; u < 2; u++) {
            int pos = tid * 2 + u;                 // 0..511
            int l15 = pos & 15, lq = (pos >> 4) & 3, g = pos >> 6;
            bf16x8_t h8, l8;
#pragma unroll
            for (int j = 0; j < 8; j++) {
                float x = ls[(g * 16 + l15) * 33 + lq * 8 + j];
                h8[j] = bhi(x);
                l8[j] = blo(x);
            }
            size_t off = (size_t)(s * 512 + pos) * 8;
            *(bf16x8_t*)(pwmhi + off) = h8;
            *(bf16x8_t*)(pwmlo + off) = l8;
        }
    } else if (bx < 24) {
        int f0 = (bx - 16) * 128;
        for (int i = tid; i < 8192; i += 256) {
            int kc = i >> 7, f = i & 127;
            ls[f * 65 + kc] = (kc < 62) ? Wconv[kc * FF + f0 + f] : 0.f;
        }
        __syncthreads();
        int f = tid >> 1, half = tid & 1;
#pragma unroll
        for (int g = 0; g < 4; g++) {
            bf16x8_t h8, l8;
#pragma unroll
            for (int j = 0; j < 8; j++) {
                float x = ls[f * 65 + half * 32 + g * 8 + j];
                h8[j] = bhi(x);
                l8[j] = blo(x);
            }
            size_t off = (size_t)(f0 + f) * 64 + half * 32 + g * 8;
            *(bf16x8_t*)(wcthi + off) = h8;
            *(bf16x8_t*)(wctlo + off) = l8;
        }
    } else if (bx < 56) {
        int s2 = bx - 24, t0 = s2 * 32;
        for (int i = tid; i < 4096; i += 256) {
            int tt = i >> 7, a = i & 127;
            ls[a * 33 + tt] = Wloc[(t0 + tt) * AA + a];
        }
        __syncthreads();
#pragma unroll
        for (int u = 0; u < 2; u++) {
            int pos = tid * 2 + u;
            int l15 = pos & 15, lq = (pos >> 4) & 3, g = pos >> 6;
            bf16x8_t h8, l8;
#pragma unroll
            for (int j = 0; j < 8; j++) {
                float x = ls[(g * 16 + l15) * 33 + lq * 8 + j];
                h8[j] = bhi(x);
                l8[j] = blo(x);
            }
            size_t off = (size_t)(s2 * 512 + pos) * 8;
            *(bf16x8_t*)(pwlhi + off) = h8;
            *(bf16x8_t*)(pwllo + off) = l8;
        }
    } else {
        int b = bx - 56;
        int a = tid & 127, half = tid >> 7;
        const float* qrow = query + b * DQ + half * 512;
        float a0 = 0.f, a1 = 0.f, a2 = 0.f, a3 = 0.f;
        for (int d = 0; d < 512; d += 4) {
            float4 qv = *(const float4*)(qrow + d);
            int dg = (half * 512 + d) * AA + a;
            a0 += qv.x * Wq[dg];
            a1 += qv.y * Wq[dg + AA];
            a2 += qv.z * Wq[dg + 2 * AA];
            a3 += qv.w * Wq[dg + 3 * AA];
        }
        ls[tid] = a0 + a1 + a2 + a3;
        __syncthreads();
        if (half == 0) q_ws[b * AA + a] = ftanh(ls[a] + ls[a + 128]);
    }
}

// ---------------- K_zq: z[b][kc][a] = sum_t X[kc][t]*Wloc[t][a] via MFMA ----------------
// B frags from packed pwl (coalesced). Output transposed bf16 hi/lo [b][a][64].
__global__ __launch_bounds__(256) void k_zq(
    const float* __restrict__ xcat,
    const __bf16* __restrict__ pwlhi, const __bf16* __restrict__ pwllo,
    __bf16* __restrict__ zthi, __bf16* __restrict__ ztlo) {
    int b = blockIdx.x, tid = threadIdx.x;
    __shared__ float xs0[1056], xs1[1056];
    __shared__ float zs[64 * 132];
    for (int i = tid; i < 1056; i += 256) {
        int t = i - 16;
        float2 xv = (t >= 0 && t < TT) ? *(const float2*)(xcat + (size_t)(b * TT + t) * 2)
                                       : make_float2(0.f, 0.f);
        xs0[i] = xv.x;
        xs1[i] = xv.y;
    }
    __syncthreads();
    int lane = tid & 63, wid = tid >> 6;
    int wm = wid >> 1, wn = wid & 1;
    int l15 = lane & 15, lq = lane >> 4;

    f32x4_t zacc[2][4];
#pragma unroll
    for (int mi = 0; mi < 2; mi++)
#pragma unroll
        for (int ni = 0; ni < 4; ni++) zacc[mi][ni] = (f32x4_t){0.f, 0.f, 0.f, 0.f};

    for (int s = 0; s < 32; s++) {
        int t0 = s * 32;
        bf16x8_t bh[4], bl[4];
#pragma unroll
        for (int ni = 0; ni < 4; ni++) {
            size_t poff = (size_t)((s * 8 + wn * 4 + ni) * 64 + lane) * 8;
            bh[ni] = *(const bf16x8_t*)(pwlhi + poff);
            bl[ni] = *(const bf16x8_t*)(pwllo + poff);
        }
        bf16x8_t ah[2], al[2];
#pragma unroll
        for (int mi = 0; mi < 2; mi++) {
            int kc = wm * 32 + mi * 16 + l15;
            const float* xsc = (kc & 1) ? xs1 : xs0;
            int base = t0 + lq * 8 + (kc >> 1) + 1;
#pragma unroll
            for (int j = 0; j < 8; j++) {
                float x = xsc[base + j];
                ah[mi][j] = bhi(x);
                al[mi][j] = blo(x);
            }
        }
#pragma unroll
        for (int ni = 0; ni < 4; ni++)
#pragma unroll
            for (int mi = 0; mi < 2; mi++) {
                zacc[mi][ni] = __builtin_amdgcn_mfma_f32_16x16x32_bf16(ah[mi], bh[ni], zacc[mi][ni], 0, 0, 0);
                zacc[mi][ni] = __builtin_amdgcn_mfma_f32_16x16x32_bf16(al[mi], bh[ni], zacc[mi][ni], 0, 0, 0);
                zacc[mi][ni] = __builtin_amdgcn_mfma_f32_16x16x32_bf16(ah[mi], bl[ni], zacc[mi][ni], 0, 0, 0);
            }
    }
#pragma unroll
    for (int mi = 0; mi < 2; mi++)
#pragma unroll
        for (int ni = 0; ni < 4; ni++)
#pragma unroll
            for (int r = 0; r < 4; r++)
                zs[(wm * 32 + mi * 16 + lq * 4 + r) * 132 + wn * 64 + ni * 16 + l15] = zacc[mi][ni][r];
    __syncthreads();
    int a = tid >> 1, half = tid & 1;
#pragma unroll
    for (int g = 0; g < 4; g++) {
        bf16x8_t h8, l8;
#pragma unroll
        for (int j = 0; j < 8; j++) {
            float x = zs[(half * 32 + g * 8 + j) * 132 + a];
            h8[j] = bhi(x);
            l8[j] = blo(x);
        }
        size_t off = ((size_t)b * AA + a) * 64 + half * 32 + g * 8;
        *(bf16x8_t*)(zthi + off) = h8;
        *(bf16x8_t*)(ztlo + off) = l8;
    }
}

// ---------------- K_main: v = tanh(value@Wm), loc = tanh(wct@z), fused score ----------------
// Barrier-free, instruction-level pipelined: all 12 loads per iteration are issued as
// asm-volatile global_load_dwordx4 (mutual program order guaranteed), then a hand-counted
// s_waitcnt vmcnt(12) waits only for the PREVIOUS iteration's loads, keeping the next
// iteration's 12 in flight (T4 counted-vmcnt, no compiler drain). sched_barrier(0) after
// the waitcnt keeps converts/MFMAs from hoisting above it (learn_hip rule #18).
// Round-2/4 evidence: compiler-managed loads gave VGPR=68 (no live prefetch buffers) and
// ~350cy serial latency per load; IR-level fences did not change codegen.
__global__ __launch_bounds__(256, 3) void k_main(
    const float* __restrict__ value,
    const __bf16* __restrict__ pwmhi, const __bf16* __restrict__ pwmlo,
    const __bf16* __restrict__ wcthi, const __bf16* __restrict__ wctlo,
    const __bf16* __restrict__ zthi, const __bf16* __restrict__ ztlo,
    const float* __restrict__ q_ws, const float* __restrict__ Wv,
    _Float16* __restrict__ v_ws, float* __restrict__ score) {
    int b = blockIdx.x >> 4;
    int trow0 = (blockIdx.x & 15) << 6;
    int tid = threadIdx.x;
    int lane = tid & 63, wid = tid >> 6;
    int wm = wid >> 1, wn = wid & 1;
    int l15 = lane & 15, lq = lane >> 4;

    __shared__ float sc_red[128];

    f32x4_t acc[2][4];
#pragma unroll
    for (int mi = 0; mi < 2; mi++)
#pragma unroll
        for (int ni = 0; ni < 4; ni++) acc[mi][ni] = (f32x4_t){0.f, 0.f, 0.f, 0.f};

    // per-lane A row pointers: row t = trow0 + wm*32 + mi*16 + l15, k-offset lq*8
    const float* a0p = value + (size_t)(b * TT + trow0 + wm * 32 + l15) * DV + lq * 8;
    const float* a1p = a0p + (size_t)16 * DV;
    // per-lane B base: element (wn*4*64 + lane)*8; ni step = 1024B imm, it step = 8192B
    const __bf16* pbh = pwmhi + (size_t)(wn * 4 * 64 + lane) * 8;
    const __bf16* pbl = pwmlo + (size_t)(wn * 4 * 64 + lane) * 8;

    f32x4_t fa[2][2][2];          // [buf][row(mi)][half]
    bf16x8_t bhb[2][4], blb[2][4];  // [buf][ni]

#define GL4(dst, ptr, OFF) \
    asm volatile("global_load_dwordx4 %0, %1, off offset:" OFF : "=v"(dst) : "v"(ptr))

    // prologue: issue L(0), 12 loads
    GL4(fa[0][0][0], a0p, "0");
    GL4(fa[0][0][1], a0p, "16");
    GL4(fa[0][1][0], a1p, "0");
    GL4(fa[0][1][1], a1p, "16");
    GL4(bhb[0][0], pbh, "0");
    GL4(bhb[0][1], pbh, "1024");
    GL4(bhb[0][2], pbh, "2048");
    GL4(bhb[0][3], pbh, "3072");
    GL4(blb[0][0], pbl, "0");
    GL4(blb[0][1], pbl, "1024");
    GL4(blb[0][2], pbl, "2048");
    GL4(blb[0][3], pbl, "3072");
    a0p += 32; a1p += 32; pbh += 4096; pbl += 4096;

#pragma unroll
    for (int it = 0; it < 16; ++it) {
        const int cur = it & 1, nxt = (it + 1) & 1;
        if (it < 15) {
            // issue L(it+1): 12 loads, program-order before the counted wait below
            GL4(fa[nxt][0][0], a0p, "0");
            GL4(fa[nxt][0][1], a0p, "16");
            GL4(fa[nxt][1][0], a1p, "0");
            GL4(fa[nxt][1][1], a1p, "16");
            GL4(bhb[nxt][0], pbh, "0");
            GL4(bhb[nxt][1], pbh, "1024");
            GL4(bhb[nxt][2], pbh, "2048");
            GL4(bhb[nxt][3], pbh, "3072");
            GL4(blb[nxt][0], pbl, "0");
            GL4(blb[nxt][1], pbl, "1024");
            GL4(blb[nxt][2], pbl, "2048");
            GL4(blb[nxt][3], pbl, "3072");
            a0p += 32; a1p += 32; pbh += 4096; pbl += 4096;
            asm volatile("s_waitcnt vmcnt(12)");   // L(it) done; L(it+1) stays in flight
        } else {
            asm volatile("s_waitcnt vmcnt(0)");    // drain before compiler-managed epilogue
        }
        __builtin_amdgcn_sched_barrier(0);

        bf16x8_t ah[2], al[2];
#pragma unroll
        for (int mi = 0; mi < 2; mi++)
#pragma unroll
            for (int h = 0; h < 2; h++)
#pragma unroll
                for (int j = 0; j < 4; j++) {
                    float x = fa[cur][mi][h][j];
                    ah[mi][h * 4 + j] = bhi(x);
                    al[mi][h * 4 + j] = blo(x);
                }
#pragma unroll
        for (int mi = 0; mi < 2; mi++)
#pragma unroll
            for (int ni = 0; ni < 4; ni++) {
                acc[mi][ni] = __builtin_amdgcn_mfma_f32_16x16x32_bf16(ah[mi], bhb[cur][ni], acc[mi][ni], 0, 0, 0);
                acc[mi][ni] = __builtin_amdgcn_mfma_f32_16x16x32_bf16(al[mi], bhb[cur][ni], acc[mi][ni], 0, 0, 0);
                acc[mi][ni] = __builtin_amdgcn_mfma_f32_16x16x32_bf16(ah[mi], blb[cur][ni], acc[mi][ni], 0, 0, 0);
            }
    }
#undef GL4

    // ---- loc gemm: K=64, kc 62/63 zero-padded in wct (compiler-managed loads) ----
    f32x4_t lacc[2][4];
#pragma unroll
    for (int mi = 0; mi < 2; mi++)
#pragma unroll
        for (int ni = 0; ni < 4; ni++) lacc[mi][ni] = (f32x4_t){0.f, 0.f, 0.f, 0.f};
#pragma unroll
    for (int kc0 = 0; kc0 < 64; kc0 += 32) {
        bf16x8_t a2h[2], a2l[2], b2h[4], b2l[4];
#pragma unroll
        for (int mi = 0; mi < 2; mi++) {
            int f = trow0 + wm * 32 + mi * 16 + l15;
            a2h[mi] = *(const bf16x8_t*)(wcthi + (size_t)f * 64 + kc0 + lq * 8);
            a2l[mi] = *(const bf16x8_t*)(wctlo + (size_t)f * 64 + kc0 + lq * 8);
        }
#pragma unroll
        for (int ni = 0; ni < 4; ni++) {
            int a = wn * 64 + ni * 16 + l15;
            size_t off = ((size_t)b * AA + a) * 64 + kc0 + lq * 8;
            b2h[ni] = *(const bf16x8_t*)(zthi + off);
            b2l[ni] = *(const bf16x8_t*)(ztlo + off);
        }
#pragma unroll
        for (int mi = 0; mi < 2; mi++)
#pragma unroll
            for (int ni = 0; ni < 4; ni++) {
                lacc[mi][ni] = __builtin_amdgcn_mfma_f32_16x16x32_bf16(a2h[mi], b2h[ni], lacc[mi][ni], 0, 0, 0);
                lacc[mi][ni] = __builtin_amdgcn_mfma_f32_16x16x32_bf16(a2l[mi], b2h[ni], lacc[mi][ni], 0, 0, 0);
                lacc[mi][ni] = __builtin_amdgcn_mfma_f32_16x16x32_bf16(a2h[mi], b2l[ni], lacc[mi][ni], 0, 0, 0);
            }
    }

    // ---- epilogue ----
    float qv[4], wv[4];
#pragma unroll
    for (int ni = 0; ni < 4; ni++) {
        int a = wn * 64 + ni * 16 + l15;
        qv[ni] = q_ws[b * AA + a];
        wv[ni] = Wv[a];
    }
#pragma unroll
    for (int mi = 0; mi < 2; mi++) {
#pragma unroll
        for (int r = 0; r < 4; r++) {
            int tl = wm * 32 + mi * 16 + lq * 4 + r;
            int t = trow0 + tl;
            float s = 0.f;
#pragma unroll
            for (int ni = 0; ni < 4; ni++) {
                float v = ftanh(acc[mi][ni][r]);
                float loc = ftanh(lacc[mi][ni][r]);
                int a = wn * 64 + ni * 16 + l15;
                v_ws[(size_t)(b * TT + t) * AA + a] = (_Float16)v;
                s += ftanh(qv[ni] + v + loc) * wv[ni];
            }
            s += __shfl_xor(s, 1, 64);
            s += __shfl_xor(s, 2, 64);
            s += __shfl_xor(s, 4, 64);
            s += __shfl_xor(s, 8, 64);
            if (l15 == 0) sc_red[wn * 64 + tl] = s;
        }
    }
    __syncthreads();
    if (tid < 64) score[b * TT + trow0 + tid] = sc_red[tid] + sc_red[64 + tid];
}

// ---------------- K_softmax ----------------
__global__ void k_softmax(const float* __restrict__ score, float* __restrict__ out_align) {
    int b = blockIdx.x, tid = threadIdx.x;
    __shared__ float red[4];
    float s[4];
#pragma unroll
    for (int i = 0; i < 4; i++) s[i] = score[b * TT + tid + i * 256];
    float m = fmaxf(fmaxf(s[0], s[1]), fmaxf(s[2], s[3]));
    for (int off = 32; off; off >>= 1) m = fmaxf(m, __shfl_xor(m, off, 64));
    int wid = tid >> 6;
    if ((tid & 63) == 0) red[wid] = m;
    __syncthreads();
    float M = fmaxf(fmaxf(red[0], red[1]), fmaxf(red[2], red[3]));
    __syncthreads();
    float e[4];
    float sum = 0.f;
#pragma unroll
    for (int i = 0; i < 4; i++) { e[i] = __expf(s[i] - M); sum += e[i]; }
    for (int off = 32; off; off >>= 1) sum += __shfl_xor(sum, off, 64);
    if ((tid & 63) == 0) red[wid] = sum;
    __syncthreads();
    float inv = 1.0f / (red[0] + red[1] + red[2] + red[3]);
#pragma unroll
    for (int i = 0; i < 4; i++) out_align[b * TT + tid + i * 256] = e[i] * inv;
}

// ---------------- K_context: context[b,a] = sum_t align[b,t] * v[b,t,a] (v in f16) ----------------
__global__ void k_context(const float* __restrict__ align, const _Float16* __restrict__ v_ws,
                          float* __restrict__ out_ctx) {
    int b = blockIdx.y, t0 = blockIdx.x * 64, tid = threadIdx.x;
    int a0 = (tid & 31) * 4, tl = tid >> 5;
    __shared__ float sh[8 * 132];
    f32x4_t acc = (f32x4_t){0.f, 0.f, 0.f, 0.f};
    for (int tt = tl; tt < 64; tt += 8) {
        float w = align[b * TT + t0 + tt];
        f16x4_t vv = *(const f16x4_t*)(v_ws + (size_t)(b * TT + t0 + tt) * AA + a0);
        acc[0] += w * (float)vv[0];
        acc[1] += w * (float)vv[1];
        acc[2] += w * (float)vv[2];
        acc[3] += w * (float)vv[3];
    }
    *(f32x4_t*)&sh[tl * 132 + a0] = acc;
    __syncthreads();
    if (tid < 128) {
        float s = 0.f;
#pragma unroll
        for (int j = 0; j < 8; j++) s += sh[j * 132 + tid];
        atomicAdd(out_ctx + b * AA + tid, s);
    }
}

extern "C" void kernel_launch(void* const* d_in, const int* in_sizes, int n_in,
                              void* d_out, int out_size, void* d_ws, size_t ws_size,
                              hipStream_t stream) {
    const float* query = (const float*)d_in[0];
    const float* value = (const float*)d_in[1];
    const float* xcat  = (const float*)d_in[2];
    const float* Wq    = (const float*)d_in[3];
    const float* Wm    = (const float*)d_in[4];
    const float* Wv    = (const float*)d_in[5];
    const float* Wconv = (const float*)d_in[6];
    const float* Wloc  = (const float*)d_in[7];
    float* out = (float*)d_out;

    float* ws = (float*)d_ws;
    float* q_ws  = ws;                       // 8192
    float* sc_ws = q_ws + 8192;              // 65536
    _Float16* v_ws = (_Float16*)(sc_ws + 65536);  // 8388608 halfs = 4194304 floats
    __bf16* pwmhi = (__bf16*)(sc_ws + 65536 + 4194304);
    __bf16* pwmlo = pwmhi + 65536;
    __bf16* wcthi = pwmlo + 65536;
    __bf16* wctlo = wcthi + 65536;
    __bf16* pwlhi = wctlo + 65536;           // 131072
    __bf16* pwllo = pwlhi + 131072;
    __bf16* zthi  = pwllo + 131072;          // 524288
    __bf16* ztlo  = zthi + 524288;

    (void)hipMemsetAsync(out, 0, (size_t)8192 * 4, stream);  // context accumulated via atomics

    k_prep<<<120, 256, 0, stream>>>(Wm, Wconv, Wloc, query, Wq,
                                    pwmhi, pwmlo, wcthi, wctlo, pwlhi, pwllo, q_ws);
    k_zq<<<BB, 256, 0, stream>>>(xcat, pwlhi, pwllo, zthi, ztlo);
    k_main<<<1024, 256, 0, stream>>>(value, pwmhi, pwmlo, wcthi, wctlo, zthi, ztlo,
                                     q_ws, Wv, v_ws, sc_ws);
    k_softmax<<<BB, 256, 0, stream>>>(sc_ws, out + 8192);
    k_context<<<dim3(16, BB), 256, 0, stream>>>(out + 8192, v_ws, out);
}

// Round 6
// 286.561 us; speedup vs baseline: 1.1006x; 1.0632x over previous
//
#include <hip/hip_runtime.h>
#include <hip/hip_bf16.h>

#define BB 64
#define TT 1024
#define AA 128
#define FF 1024
#define DQ 1024
#define DV 512

typedef __bf16 bf16x8_t __attribute__((ext_vector_type(8)));
typedef __bf16 bf16x4_t __attribute__((ext_vector_type(4)));
typedef float f32x4_t __attribute__((ext_vector_type(4)));
typedef _Float16 f16x4_t __attribute__((ext_vector_type(4)));

__device__ __forceinline__ float ftanh(float x) {
    float e = __expf(2.0f * x);
    return 1.0f - 2.0f / (e + 1.0f);
}

__device__ __forceinline__ __bf16 bhi(float x) { return (__bf16)x; }
__device__ __forceinline__ __bf16 blo(float x) {
    __bf16 h = (__bf16)x;
    return (__bf16)(x - (float)h);
}

// ---------------- K_prep ----------------
// blocks 0..15:  Wm slab s (32 d) -> packed pwm hi/lo, fragment order
//                P[((s*8+g)*64 + lane)*8 + j] = Wm[s*32 + (lane>>4)*8 + j][g*16 + (lane&15)]
// blocks 16..23: Wconv -> wct[f][64] hi/lo (kc padded to 64)
// blocks 24..55: Wloc slab s2 (32 t) -> packed pwl hi/lo, same fragment order over t
// blocks 56..119: query GEMM (1 b each)
__global__ __launch_bounds__(256) void k_prep(
    const float* __restrict__ Wm, const float* __restrict__ Wconv,
    const float* __restrict__ Wloc, const float* __restrict__ query,
    const float* __restrict__ Wq,
    __bf16* __restrict__ pwmhi, __bf16* __restrict__ pwmlo,
    __bf16* __restrict__ wcthi, __bf16* __restrict__ wctlo,
    __bf16* __restrict__ pwlhi, __bf16* __restrict__ pwllo,
    float* __restrict__ q_ws) {
    __shared__ float ls[128 * 65];
    int bx = blockIdx.x, tid = threadIdx.x;
    if (bx < 16) {
        int s = bx, d0 = s * 32;
        for (int i = tid; i < 4096; i += 256) {
            int dd = i >> 7, a = i & 127;
            ls[a * 33 + dd] = Wm[(d0 + dd) * AA + a];
        }
        __syncthreads();
#pragma unroll
        for (int u = 0; u < 2; u++) {
            int pos = tid * 2 + u;                 // 0..511
            int l15 = pos & 15, lq = (pos >> 4) & 3, g = pos >> 6;
            bf16x8_t h8, l8;
#pragma unroll
            for (int j = 0; j < 8; j++) {
                float x = ls[(g * 16 + l15) * 33 + lq * 8 + j];
                h8[j] = bhi(x);
                l8[j] = blo(x);
            }
            size_t off = (size_t)(s * 512 + pos) * 8;
            *(bf16x8_t*)(pwmhi + off) = h8;
            *(bf16x8_t*)(pwmlo + off) = l8;
        }
    } else if (bx < 24) {
        int f0 = (bx - 16) * 128;
        for (int i = tid; i < 8192; i += 256) {
            int kc = i >> 7, f = i & 127;
            ls[f * 65 + kc] = (kc < 62) ? Wconv[kc * FF + f0 + f] : 0.f;
        }
        __syncthreads();
        int f = tid >> 1, half = tid & 1;
#pragma unroll
        for (int g = 0; g < 4; g++) {
            bf16x8_t h8, l8;
#pragma unroll
            for (int j = 0; j < 8; j++) {
                float x = ls[f * 65 + half * 32 + g * 8 + j];
                h8[j] = bhi(x);
                l8[j] = blo(x);
            }
            size_t off = (size_t)(f0 + f) * 64 + half * 32 + g * 8;
            *(bf16x8_t*)(wcthi + off) = h8;
            *(bf16x8_t*)(wctlo + off) = l8;
        }
    } else if (bx < 56) {
        int s2 = bx - 24, t0 = s2 * 32;
        for (int i = tid; i < 4096; i += 256) {
            int tt = i >> 7, a = i & 127;
            ls[a * 33 + tt] = Wloc[(t0 + tt) * AA + a];
        }
        __syncthreads();
#pragma unroll
        for (int u = 0; u < 2; u++) {
            int pos = tid * 2 + u;
            int l15 = pos & 15, lq = (pos >> 4) & 3, g = pos >> 6;
            bf16x8_t h8, l8;
#pragma unroll
            for (int j = 0; j < 8; j++) {
                float x = ls[(g * 16 + l15) * 33 + lq * 8 + j];
                h8[j] = bhi(x);
                l8[j] = blo(x);
            }
            size_t off = (size_t)(s2 * 512 + pos) * 8;
            *(bf16x8_t*)(pwlhi + off) = h8;
            *(bf16x8_t*)(pwllo + off) = l8;
        }
    } else {
        int b = bx - 56;
        int a = tid & 127, half = tid >> 7;
        const float* qrow = query + b * DQ + half * 512;
        float a0 = 0.f, a1 = 0.f, a2 = 0.f, a3 = 0.f;
        for (int d = 0; d < 512; d += 4) {
            float4 qv = *(const float4*)(qrow + d);
            int dg = (half * 512 + d) * AA + a;
            a0 += qv.x * Wq[dg];
            a1 += qv.y * Wq[dg + AA];
            a2 += qv.z * Wq[dg + 2 * AA];
            a3 += qv.w * Wq[dg + 3 * AA];
        }
        ls[tid] = a0 + a1 + a2 + a3;
        __syncthreads();
        if (half == 0) q_ws[b * AA + a] = ftanh(ls[a] + ls[a + 128]);
    }
}

// ---------------- K_zq: z[b][kc][a] = sum_t X[kc][t]*Wloc[t][a] via MFMA ----------------
// a-split grid (128 blocks = 64 b x 2 a-halves): halves per-block B loads, doubles TLP.
// pwl reads phase-staggered over s-slabs to avoid the all-blocks-same-line L2 hotspot.
// Output transposed bf16 hi/lo [b][a][64] (layout unchanged).
__global__ __launch_bounds__(256) void k_zq(
    const float* __restrict__ xcat,
    const __bf16* __restrict__ pwlhi, const __bf16* __restrict__ pwllo,
    __bf16* __restrict__ zthi, __bf16* __restrict__ ztlo) {
    int bx = blockIdx.x;
    int b = bx & 63, ah = bx >> 6;   // a-base = ah*64
    int tid = threadIdx.x;
    __shared__ float xs0[1056], xs1[1056];
    __shared__ float zs[64 * 66];
    for (int i = tid; i < 1056; i += 256) {
        int t = i - 16;
        float2 xv = (t >= 0 && t < TT) ? *(const float2*)(xcat + (size_t)(b * TT + t) * 2)
                                       : make_float2(0.f, 0.f);
        xs0[i] = xv.x;
        xs1[i] = xv.y;
    }
    __syncthreads();
    int lane = tid & 63, wid = tid >> 6;
    int wm = wid >> 1, wn = wid & 1;
    int l15 = lane & 15, lq = lane >> 4;

    f32x4_t zacc[2][2];
#pragma unroll
    for (int mi = 0; mi < 2; mi++)
#pragma unroll
        for (int ni = 0; ni < 2; ni++) zacc[mi][ni] = (f32x4_t){0.f, 0.f, 0.f, 0.f};

    int phase = bx & 31;
    for (int sl = 0; sl < 32; sl++) {
        int s = (sl + phase) & 31;
        int t0 = s * 32;
        bf16x8_t bh[2], bl[2];
#pragma unroll
        for (int ni = 0; ni < 2; ni++) {
            int g = ah * 4 + wn * 2 + ni;
            size_t poff = (size_t)((s * 8 + g) * 64 + lane) * 8;
            bh[ni] = *(const bf16x8_t*)(pwlhi + poff);
            bl[ni] = *(const bf16x8_t*)(pwllo + poff);
        }
        bf16x8_t ah_[2], al_[2];
#pragma unroll
        for (int mi = 0; mi < 2; mi++) {
            int kc = wm * 32 + mi * 16 + l15;
            const float* xsc = (kc & 1) ? xs1 : xs0;
            int base = t0 + lq * 8 + (kc >> 1) + 1;
#pragma unroll
            for (int j = 0; j < 8; j++) {
                float x = xsc[base + j];
                ah_[mi][j] = bhi(x);
                al_[mi][j] = blo(x);
            }
        }
#pragma unroll
        for (int ni = 0; ni < 2; ni++)
#pragma unroll
            for (int mi = 0; mi < 2; mi++) {
                zacc[mi][ni] = __builtin_amdgcn_mfma_f32_16x16x32_bf16(ah_[mi], bh[ni], zacc[mi][ni], 0, 0, 0);
                zacc[mi][ni] = __builtin_amdgcn_mfma_f32_16x16x32_bf16(al_[mi], bh[ni], zacc[mi][ni], 0, 0, 0);
                zacc[mi][ni] = __builtin_amdgcn_mfma_f32_16x16x32_bf16(ah_[mi], bl[ni], zacc[mi][ni], 0, 0, 0);
            }
    }
#pragma unroll
    for (int mi = 0; mi < 2; mi++)
#pragma unroll
        for (int ni = 0; ni < 2; ni++)
#pragma unroll
            for (int r = 0; r < 4; r++)
                zs[(wm * 32 + mi * 16 + lq * 4 + r) * 66 + wn * 32 + ni * 16 + l15] = zacc[mi][ni][r];
    __syncthreads();
    int a_local = tid & 63, seg = tid >> 6;   // seg: 16 kc each
#pragma unroll
    for (int g = 0; g < 2; g++) {
        bf16x8_t h8, l8;
#pragma unroll
        for (int j = 0; j < 8; j++) {
            float x = zs[(seg * 16 + g * 8 + j) * 66 + a_local];
            h8[j] = bhi(x);
            l8[j] = blo(x);
        }
        size_t off = ((size_t)b * AA + ah * 64 + a_local) * 64 + seg * 16 + g * 8;
        *(bf16x8_t*)(zthi + off) = h8;
        *(bf16x8_t*)(ztlo + off) = l8;
    }
}

// ---------------- K_main: v = tanh(value@Wm), loc = tanh(wct@z), fused score ----------------
// Barrier-free, asm-pipelined (R5: VGPR 84, buffers live, vmcnt(12) counted). R5 residual
// stall diagnosed as B-operand L2 hotspot: pwm addresses were block-independent, so all
// 1024 blocks hammered the same 16KB slab's L2 lines each iteration. Fix: phase-staggered
// K order (accumulation commutes) — block processes slab (it+phase)&15, spreading
// concurrent reads over the whole 256KB pwm.
__global__ __launch_bounds__(256, 3) void k_main(
    const float* __restrict__ value,
    const __bf16* __restrict__ pwmhi, const __bf16* __restrict__ pwmlo,
    const __bf16* __restrict__ wcthi, const __bf16* __restrict__ wctlo,
    const __bf16* __restrict__ zthi, const __bf16* __restrict__ ztlo,
    const float* __restrict__ q_ws, const float* __restrict__ Wv,
    _Float16* __restrict__ v_ws, float* __restrict__ score) {
    int b = blockIdx.x >> 4;
    int trow0 = (blockIdx.x & 15) << 6;
    int tid = threadIdx.x;
    int lane = tid & 63, wid = tid >> 6;
    int wm = wid >> 1, wn = wid & 1;
    int l15 = lane & 15, lq = lane >> 4;
    int phase = (blockIdx.x + (blockIdx.x >> 4)) & 15;

    __shared__ float sc_red[128];

    f32x4_t acc[2][4];
#pragma unroll
    for (int mi = 0; mi < 2; mi++)
#pragma unroll
        for (int ni = 0; ni < 4; ni++) acc[mi][ni] = (f32x4_t){0.f, 0.f, 0.f, 0.f};

    // bases (no d offset): row t = trow0 + wm*32 + mi*16 + l15, k-offset lq*8
    const float* a0b = value + (size_t)(b * TT + trow0 + wm * 32 + l15) * DV + lq * 8;
    const float* a1b = a0b + (size_t)16 * DV;
    const __bf16* pbh0 = pwmhi + (size_t)(wn * 4 * 64 + lane) * 8;
    const __bf16* pbl0 = pwmlo + (size_t)(wn * 4 * 64 + lane) * 8;

    f32x4_t fa[2][2][2];            // [buf][row(mi)][half]
    bf16x8_t bhb[2][4], blb[2][4];  // [buf][ni]

#define GL4(dst, ptr, OFF) \
    asm volatile("global_load_dwordx4 %0, %1, off offset:" OFF : "=v"(dst) : "v"(ptr))
#define ISSUE(buf, s) { \
    const float* _a0 = a0b + (s) * 32; \
    const float* _a1 = a1b + (s) * 32; \
    const __bf16* _bh = pbh0 + (size_t)(s) * 4096; \
    const __bf16* _bl = pbl0 + (size_t)(s) * 4096; \
    GL4(fa[buf][0][0], _a0, "0"); \
    GL4(fa[buf][0][1], _a0, "16"); \
    GL4(fa[buf][1][0], _a1, "0"); \
    GL4(fa[buf][1][1], _a1, "16"); \
    GL4(bhb[buf][0], _bh, "0"); \
    GL4(bhb[buf][1], _bh, "1024"); \
    GL4(bhb[buf][2], _bh, "2048"); \
    GL4(bhb[buf][3], _bh, "3072"); \
    GL4(blb[buf][0], _bl, "0"); \
    GL4(blb[buf][1], _bl, "1024"); \
    GL4(blb[buf][2], _bl, "2048"); \
    GL4(blb[buf][3], _bl, "3072"); }

    // prologue: issue slab(phase)
    ISSUE(0, phase);

#pragma unroll
    for (int it = 0; it < 16; ++it) {
        const int cur = it & 1, nxt = (it + 1) & 1;
        if (it < 15) {
            int s2 = (it + 1 + phase) & 15;
            ISSUE(nxt, s2);                        // program-order before the counted wait
            asm volatile("s_waitcnt vmcnt(12)");   // slab(it) done; next 12 stay in flight
        } else {
            asm volatile("s_waitcnt vmcnt(0)");    // drain before compiler-managed epilogue
        }
        __builtin_amdgcn_sched_barrier(0);

        bf16x8_t ah[2], al[2];
#pragma unroll
        for (int mi = 0; mi < 2; mi++)
#pragma unroll
            for (int h = 0; h < 2; h++)
#pragma unroll
                for (int j = 0; j < 4; j++) {
                    float x = fa[cur][mi][h][j];
                    ah[mi][h * 4 + j] = bhi(x);
                    al[mi][h * 4 + j] = blo(x);
                }
#pragma unroll
        for (int mi = 0; mi < 2; mi++)
#pragma unroll
            for (int ni = 0; ni < 4; ni++) {
                acc[mi][ni] = __builtin_amdgcn_mfma_f32_16x16x32_bf16(ah[mi], bhb[cur][ni], acc[mi][ni], 0, 0, 0);
                acc[mi][ni] = __builtin_amdgcn_mfma_f32_16x16x32_bf16(al[mi], bhb[cur][ni], acc[mi][ni], 0, 0, 0);
                acc[mi][ni] = __builtin_amdgcn_mfma_f32_16x16x32_bf16(ah[mi], blb[cur][ni], acc[mi][ni], 0, 0, 0);
            }
    }
#undef ISSUE
#undef GL4

    // ---- loc gemm: K=64, kc 62/63 zero-padded in wct (compiler-managed loads) ----
    f32x4_t lacc[2][4];
#pragma unroll
    for (int mi = 0; mi < 2; mi++)
#pragma unroll
        for (int ni = 0; ni < 4; ni++) lacc[mi][ni] = (f32x4_t){0.f, 0.f, 0.f, 0.f};
#pragma unroll
    for (int kc0 = 0; kc0 < 64; kc0 += 32) {
        bf16x8_t a2h[2], a2l[2], b2h[4], b2l[4];
#pragma unroll
        for (int mi = 0; mi < 2; mi++) {
            int f = trow0 + wm * 32 + mi * 16 + l15;
            a2h[mi] = *(const bf16x8_t*)(wcthi + (size_t)f * 64 + kc0 + lq * 8);
            a2l[mi] = *(const bf16x8_t*)(wctlo + (size_t)f * 64 + kc0 + lq * 8);
        }
#pragma unroll
        for (int ni = 0; ni < 4; ni++) {
            int a = wn * 64 + ni * 16 + l15;
            size_t off = ((size_t)b * AA + a) * 64 + kc0 + lq * 8;
            b2h[ni] = *(const bf16x8_t*)(zthi + off);
            b2l[ni] = *(const bf16x8_t*)(ztlo + off);
        }
#pragma unroll
        for (int mi = 0; mi < 2; mi++)
#pragma unroll
            for (int ni = 0; ni < 4; ni++) {
                lacc[mi][ni] = __builtin_amdgcn_mfma_f32_16x16x32_bf16(a2h[mi], b2h[ni], lacc[mi][ni], 0, 0, 0);
                lacc[mi][ni] = __builtin_amdgcn_mfma_f32_16x16x32_bf16(a2l[mi], b2h[ni], lacc[mi][ni], 0, 0, 0);
                lacc[mi][ni] = __builtin_amdgcn_mfma_f32_16x16x32_bf16(a2h[mi], b2l[ni], lacc[mi][ni], 0, 0, 0);
            }
    }

    // ---- epilogue ----
    float qv[4], wv[4];
#pragma unroll
    for (int ni = 0; ni < 4; ni++) {
        int a = wn * 64 + ni * 16 + l15;
        qv[ni] = q_ws[b * AA + a];
        wv[ni] = Wv[a];
    }
#pragma unroll
    for (int mi = 0; mi < 2; mi++) {
#pragma unroll
        for (int r = 0; r < 4; r++) {
            int tl = wm * 32 + mi * 16 + lq * 4 + r;
            int t = trow0 + tl;
            float s = 0.f;
#pragma unroll
            for (int ni = 0; ni < 4; ni++) {
                float v = ftanh(acc[mi][ni][r]);
                float loc = ftanh(lacc[mi][ni][r]);
                int a = wn * 64 + ni * 16 + l15;
                v_ws[(size_t)(b * TT + t) * AA + a] = (_Float16)v;
                s += ftanh(qv[ni] + v + loc) * wv[ni];
            }
            s += __shfl_xor(s, 1, 64);
            s += __shfl_xor(s, 2, 64);
            s += __shfl_xor(s, 4, 64);
            s += __shfl_xor(s, 8, 64);
            if (l15 == 0) sc_red[wn * 64 + tl] = s;
        }
    }
    __syncthreads();
    if (tid < 64) score[b * TT + trow0 + tid] = sc_red[tid] + sc_red[64 + tid];
}

// ---------------- K_softmax ----------------
__global__ void k_softmax(const float* __restrict__ score, float* __restrict__ out_align) {
    int b = blockIdx.x, tid = threadIdx.x;
    __shared__ float red[4];
    float s[4];
#pragma unroll
    for (int i = 0; i < 4; i++) s[i] = score[b * TT + tid + i * 256];
    float m = fmaxf(fmaxf(s[0], s[1]), fmaxf(s[2], s[3]));
    for (int off = 32; off; off >>= 1) m = fmaxf(m, __shfl_xor(m, off, 64));
    int wid = tid >> 6;
    if ((tid & 63) == 0) red[wid] = m;
    __syncthreads();
    float M = fmaxf(fmaxf(red[0], red[1]), fmaxf(red[2], red[3]));
    __syncthreads();
    float e[4];
    float sum = 0.f;
#pragma unroll
    for (int i = 0; i < 4; i++) { e[i] = __expf(s[i] - M); sum += e[i]; }
    for (int off = 32; off; off >>= 1) sum += __shfl_xor(sum, off, 64);
    if ((tid & 63) == 0) red[wid] = sum;
    __syncthreads();
    float inv = 1.0f / (red[0] + red[1] + red[2] + red[3]);
#pragma unroll
    for (int i = 0; i < 4; i++) out_align[b * TT + tid + i * 256] = e[i] * inv;
}

// ---------------- K_context: context[b,a] = sum_t align[b,t] * v[b,t,a] (v in f16) ----------------
__global__ void k_context(const float* __restrict__ align, const _Float16* __restrict__ v_ws,
                          float* __restrict__ out_ctx) {
    int b = blockIdx.y, t0 = blockIdx.x * 64, tid = threadIdx.x;
    int a0 = (tid & 31) * 4, tl = tid >> 5;
    __shared__ float sh[8 * 132];
    f32x4_t acc = (f32x4_t){0.f, 0.f, 0.f, 0.f};
    for (int tt = tl; tt < 64; tt += 8) {
        float w = align[b * TT + t0 + tt];
        f16x4_t vv = *(const f16x4_t*)(v_ws + (size_t)(b * TT + t0 + tt) * AA + a0);
        acc[0] += w * (float)vv[0];
        acc[1] += w * (float)vv[1];
        acc[2] += w * (float)vv[2];
        acc[3] += w * (float)vv[3];
    }
    *(f32x4_t*)&sh[tl * 132 + a0] = acc;
    __syncthreads();
    if (tid < 128) {
        float s = 0.f;
#pragma unroll
        for (int j = 0; j < 8; j++) s += sh[j * 132 + tid];
        atomicAdd(out_ctx + b * AA + tid, s);
    }
}

extern "C" void kernel_launch(void* const* d_in, const int* in_sizes, int n_in,
                              void* d_out, int out_size, void* d_ws, size_t ws_size,
                              hipStream_t stream) {
    const float* query = (const float*)d_in[0];
    const float* value = (const float*)d_in[1];
    const float* xcat  = (const float*)d_in[2];
    const float* Wq    = (const float*)d_in[3];
    const float* Wm    = (const float*)d_in[4];
    const float* Wv    = (const float*)d_in[5];
    const float* Wconv = (const float*)d_in[6];
    const float* Wloc  = (const float*)d_in[7];
    float* out = (float*)d_out;

    float* ws = (float*)d_ws;
    float* q_ws  = ws;                       // 8192
    float* sc_ws = q_ws + 8192;              // 65536
    _Float16* v_ws = (_Float16*)(sc_ws + 65536);  // 8388608 halfs = 4194304 floats
    __bf16* pwmhi = (__bf16*)(sc_ws + 65536 + 4194304);
    __bf16* pwmlo = pwmhi + 65536;
    __bf16* wcthi = pwmlo + 65536;
    __bf16* wctlo = wcthi + 65536;
    __bf16* pwlhi = wctlo + 65536;           // 131072
    __bf16* pwllo = pwlhi + 131072;
    __bf16* zthi  = pwllo + 131072;          // 524288
    __bf16* ztlo  = zthi + 524288;

    (void)hipMemsetAsync(out, 0, (size_t)8192 * 4, stream);  // context accumulated via atomics

    k_prep<<<120, 256, 0, stream>>>(Wm, Wconv, Wloc, query, Wq,
                                    pwmhi, pwmlo, wcthi, wctlo, pwlhi, pwllo, q_ws);
    k_zq<<<128, 256, 0, stream>>>(xcat, pwlhi, pwllo, zthi, ztlo);
    k_main<<<1024, 256, 0, stream>>>(value, pwmhi, pwmlo, wcthi, wctlo, zthi, ztlo,
                                     q_ws, Wv, v_ws, sc_ws);
    k_softmax<<<BB, 256, 0, stream>>>(sc_ws, out + 8192);
    k_context<<<dim3(16, BB), 256, 0, stream>>>(out + 8192, v_ws, out);
}

// Round 7
// 268.397 us; speedup vs baseline: 1.1750x; 1.0677x over previous
//
#include <hip/hip_runtime.h>
#include <hip/hip_bf16.h>

#define BB 64
#define TT 1024
#define AA 128
#define FF 1024
#define DQ 1024
#define DV 512

typedef __bf16 bf16x8_t __attribute__((ext_vector_type(8)));
typedef __bf16 bf16x4_t __attribute__((ext_vector_type(4)));
typedef float f32x4_t __attribute__((ext_vector_type(4)));
typedef _Float16 f16x4_t __attribute__((ext_vector_type(4)));

__device__ __forceinline__ float ftanh(float x) {
    float e = __expf(2.0f * x);
    return 1.0f - 2.0f / (e + 1.0f);
}

__device__ __forceinline__ __bf16 bhi(float x) { return (__bf16)x; }
__device__ __forceinline__ __bf16 blo(float x) {
    __bf16 h = (__bf16)x;
    return (__bf16)(x - (float)h);
}

// ---------------- K_prep ----------------
__global__ __launch_bounds__(256) void k_prep(
    const float* __restrict__ Wm, const float* __restrict__ Wconv,
    const float* __restrict__ Wloc, const float* __restrict__ query,
    const float* __restrict__ Wq,
    __bf16* __restrict__ pwmhi, __bf16* __restrict__ pwmlo,
    __bf16* __restrict__ wcthi, __bf16* __restrict__ wctlo,
    __bf16* __restrict__ pwlhi, __bf16* __restrict__ pwllo,
    float* __restrict__ q_ws) {
    __shared__ float ls[128 * 65];
    int bx = blockIdx.x, tid = threadIdx.x;
    if (bx < 16) {
        int s = bx, d0 = s * 32;
        for (int i = tid; i < 4096; i += 256) {
            int dd = i >> 7, a = i & 127;
            ls[a * 33 + dd] = Wm[(d0 + dd) * AA + a];
        }
        __syncthreads();
#pragma unroll
        for (int u = 0; u < 2; u++) {
            int pos = tid * 2 + u;                 // 0..511
            int l15 = pos & 15, lq = (pos >> 4) & 3, g = pos >> 6;
            bf16x8_t h8, l8;
#pragma unroll
            for (int j = 0; j < 8; j++) {
                float x = ls[(g * 16 + l15) * 33 + lq * 8 + j];
                h8[j] = bhi(x);
                l8[j] = blo(x);
            }
            size_t off = (size_t)(s * 512 + pos) * 8;
            *(bf16x8_t*)(pwmhi + off) = h8;
            *(bf16x8_t*)(pwmlo + off) = l8;
        }
    } else if (bx < 24) {
        int f0 = (bx - 16) * 128;
        for (int i = tid; i < 8192; i += 256) {
            int kc = i >> 7, f = i & 127;
            ls[f * 65 + kc] = (kc < 62) ? Wconv[kc * FF + f0 + f] : 0.f;
        }
        __syncthreads();
        int f = tid >> 1, half = tid & 1;
#pragma unroll
        for (int g = 0; g < 4; g++) {
            bf16x8_t h8, l8;
#pragma unroll
            for (int j = 0; j < 8; j++) {
                float x = ls[f * 65 + half * 32 + g * 8 + j];
                h8[j] = bhi(x);
                l8[j] = blo(x);
            }
            size_t off = (size_t)(f0 + f) * 64 + half * 32 + g * 8;
            *(bf16x8_t*)(wcthi + off) = h8;
            *(bf16x8_t*)(wctlo + off) = l8;
        }
    } else if (bx < 56) {
        int s2 = bx - 24, t0 = s2 * 32;
        for (int i = tid; i < 4096; i += 256) {
            int tt = i >> 7, a = i & 127;
            ls[a * 33 + tt] = Wloc[(t0 + tt) * AA + a];
        }
        __syncthreads();
#pragma unroll
        for (int u = 0; u < 2; u++) {
            int pos = tid * 2 + u;
            int l15 = pos & 15, lq = (pos >> 4) & 3, g = pos >> 6;
            bf16x8_t h8, l8;
#pragma unroll
            for (int j = 0; j < 8; j++) {
                float x = ls[(g * 16 + l15) * 33 + lq * 8 + j];
                h8[j] = bhi(x);
                l8[j] = blo(x);
            }
            size_t off = (size_t)(s2 * 512 + pos) * 8;
            *(bf16x8_t*)(pwlhi + off) = h8;
            *(bf16x8_t*)(pwllo + off) = l8;
        }
    } else {
        int b = bx - 56;
        int a = tid & 127, half = tid >> 7;
        const float* qrow = query + b * DQ + half * 512;
        float a0 = 0.f, a1 = 0.f, a2 = 0.f, a3 = 0.f;
        for (int d = 0; d < 512; d += 4) {
            float4 qv = *(const float4*)(qrow + d);
            int dg = (half * 512 + d) * AA + a;
            a0 += qv.x * Wq[dg];
            a1 += qv.y * Wq[dg + AA];
            a2 += qv.z * Wq[dg + 2 * AA];
            a3 += qv.w * Wq[dg + 3 * AA];
        }
        ls[tid] = a0 + a1 + a2 + a3;
        __syncthreads();
        if (half == 0) q_ws[b * AA + a] = ftanh(ls[a] + ls[a + 128]);
    }
}

// ---------------- K_zq (unchanged from round 5) ----------------
__global__ __launch_bounds__(256) void k_zq(
    const float* __restrict__ xcat,
    const __bf16* __restrict__ pwlhi, const __bf16* __restrict__ pwllo,
    __bf16* __restrict__ zthi, __bf16* __restrict__ ztlo) {
    int bx = blockIdx.x;
    int b = bx & 63, ah = bx >> 6;   // a-base = ah*64
    int tid = threadIdx.x;
    __shared__ float xs0[1056], xs1[1056];
    __shared__ float zs[64 * 66];
    for (int i = tid; i < 1056; i += 256) {
        int t = i - 16;
        float2 xv = (t >= 0 && t < TT) ? *(const float2*)(xcat + (size_t)(b * TT + t) * 2)
                                       : make_float2(0.f, 0.f);
        xs0[i] = xv.x;
        xs1[i] = xv.y;
    }
    __syncthreads();
    int lane = tid & 63, wid = tid >> 6;
    int wm = wid >> 1, wn = wid & 1;
    int l15 = lane & 15, lq = lane >> 4;

    f32x4_t zacc[2][2];
#pragma unroll
    for (int mi = 0; mi < 2; mi++)
#pragma unroll
        for (int ni = 0; ni < 2; ni++) zacc[mi][ni] = (f32x4_t){0.f, 0.f, 0.f, 0.f};

    int phase = bx & 31;
    for (int sl = 0; sl < 32; sl++) {
        int s = (sl + phase) & 31;
        int t0 = s * 32;
        bf16x8_t bh[2], bl[2];
#pragma unroll
        for (int ni = 0; ni < 2; ni++) {
            int g = ah * 4 + wn * 2 + ni;
            size_t poff = (size_t)((s * 8 + g) * 64 + lane) * 8;
            bh[ni] = *(const bf16x8_t*)(pwlhi + poff);
            bl[ni] = *(const bf16x8_t*)(pwllo + poff);
        }
        bf16x8_t ah_[2], al_[2];
#pragma unroll
        for (int mi = 0; mi < 2; mi++) {
            int kc = wm * 32 + mi * 16 + l15;
            const float* xsc = (kc & 1) ? xs1 : xs0;
            int base = t0 + lq * 8 + (kc >> 1) + 1;
#pragma unroll
            for (int j = 0; j < 8; j++) {
                float x = xsc[base + j];
                ah_[mi][j] = bhi(x);
                al_[mi][j] = blo(x);
            }
        }
#pragma unroll
        for (int ni = 0; ni < 2; ni++)
#pragma unroll
            for (int mi = 0; mi < 2; mi++) {
                zacc[mi][ni] = __builtin_amdgcn_mfma_f32_16x16x32_bf16(ah_[mi], bh[ni], zacc[mi][ni], 0, 0, 0);
                zacc[mi][ni] = __builtin_amdgcn_mfma_f32_16x16x32_bf16(al_[mi], bh[ni], zacc[mi][ni], 0, 0, 0);
                zacc[mi][ni] = __builtin_amdgcn_mfma_f32_16x16x32_bf16(ah_[mi], bl[ni], zacc[mi][ni], 0, 0, 0);
            }
    }
#pragma unroll
    for (int mi = 0; mi < 2; mi++)
#pragma unroll
        for (int ni = 0; ni < 2; ni++)
#pragma unroll
            for (int r = 0; r < 4; r++)
                zs[(wm * 32 + mi * 16 + lq * 4 + r) * 66 + wn * 32 + ni * 16 + l15] = zacc[mi][ni][r];
    __syncthreads();
    int a_local = tid & 63, seg = tid >> 6;   // seg: 16 kc each
#pragma unroll
    for (int g = 0; g < 2; g++) {
        bf16x8_t h8, l8;
#pragma unroll
        for (int j = 0; j < 8; j++) {
            float x = zs[(seg * 16 + g * 8 + j) * 66 + a_local];
            h8[j] = bhi(x);
            l8[j] = blo(x);
        }
        size_t off = ((size_t)b * AA + ah * 64 + a_local) * 64 + seg * 16 + g * 8;
        *(bf16x8_t*)(zthi + off) = h8;
        *(bf16x8_t*)(ztlo + off) = l8;
    }
}

// ---------------- K_main: 2-phase LDS-staged GEMM (T3-minimal template) ----------------
// BM=128 x BN=128 x BK=32, 512 blocks (64 b x 8 t-slices), 4 waves 2x2 (each 64x64).
// A (raw f32, 16KB/step) + B (packed hi/lo, 16KB/step) staged via global_load_lds,
// double-buffered (64KB LDS). Each block fetches A ONCE (no wn duplication) and B once
// -> total global read ~260MB vs R6's ~780MB of per-wave requests. A-tile LDS uses
// both-sides XOR swizzle (unit u at row r holds global unit u^(r&7)) to kill the
// 16-way row-stride-128B bank conflict; B is fragment-linear (consecutive-16B, benign).
__global__ __launch_bounds__(256, 2) void k_main(
    const float* __restrict__ value,
    const __bf16* __restrict__ pwmhi, const __bf16* __restrict__ pwmlo,
    const __bf16* __restrict__ wcthi, const __bf16* __restrict__ wctlo,
    const __bf16* __restrict__ zthi, const __bf16* __restrict__ ztlo,
    const float* __restrict__ q_ws, const float* __restrict__ Wv,
    _Float16* __restrict__ v_ws, float* __restrict__ score) {
    int b = blockIdx.x >> 3;
    int trow0 = (blockIdx.x & 7) << 7;
    int tid = threadIdx.x;
    int lane = tid & 63, wid = tid >> 6;
    int wm = wid >> 1, wn = wid & 1;
    int l15 = lane & 15, lq = lane >> 4;

    __shared__ __align__(16) float As[2][128 * 32];     // 16 KB per buf
    __shared__ __align__(16) __bf16 Bh[2][512 * 8];     // 8 KB per buf
    __shared__ __align__(16) __bf16 Bl[2][512 * 8];     // 8 KB per buf
    __shared__ float sc_red[256];

    f32x4_t acc[4][4];
#pragma unroll
    for (int mi = 0; mi < 4; mi++)
#pragma unroll
        for (int ni = 0; ni < 4; ni++) acc[mi][ni] = (f32x4_t){0.f, 0.f, 0.f, 0.f};

    // ---- staging address setup ----
    // A: instr i (0..3): chunk c=(wid*4+i)*64+lane -> row=c>>3, unit u=lane&7.
    //    Pre-swizzled global unit = u ^ (lane>>3)   [row&7 == lane>>3]
    int l3 = lane >> 3;
    int su = (lane & 7) ^ l3;
    const float* aG[4];
    unsigned aL[4];
#pragma unroll
    for (int i = 0; i < 4; i++) {
        int row = (wid * 4 + i) * 8 + l3;
        aG[i] = value + (size_t)(b * TT + trow0 + row) * DV + su * 4;
        aL[i] = (unsigned)((wid * 4 + i) * 1024);   // byte offset in As buf
    }
    // B: instr j (0..1): chunk c=(wid*2+j)*64+lane, global contiguous
    const __bf16* bGh[2];
    const __bf16* bGl[2];
    unsigned bL[2];
#pragma unroll
    for (int j = 0; j < 2; j++) {
        int c = (wid * 2 + j) * 64 + lane;
        bGh[j] = pwmhi + (size_t)c * 8;
        bGl[j] = pwmlo + (size_t)c * 8;
        bL[j] = (unsigned)((wid * 2 + j) * 1024);
    }

#define STAGE(bf, s)                                                                        \
    {                                                                                       \
        _Pragma("unroll") for (int i = 0; i < 4; i++)                                       \
            __builtin_amdgcn_global_load_lds(                                               \
                (const __attribute__((address_space(1))) void*)(aG[i] + (s) * 32),          \
                (__attribute__((address_space(3))) void*)((char*)&As[bf][0] + aL[i]),       \
                16, 0, 0);                                                                  \
        _Pragma("unroll") for (int j = 0; j < 2; j++) {                                     \
            __builtin_amdgcn_global_load_lds(                                               \
                (const __attribute__((address_space(1))) void*)(bGh[j] + (size_t)(s) * 4096),\
                (__attribute__((address_space(3))) void*)((char*)&Bh[bf][0] + bL[j]),       \
                16, 0, 0);                                                                  \
            __builtin_amdgcn_global_load_lds(                                               \
                (const __attribute__((address_space(1))) void*)(bGl[j] + (size_t)(s) * 4096),\
                (__attribute__((address_space(3))) void*)((char*)&Bl[bf][0] + bL[j]),       \
                16, 0, 0);                                                                  \
        }                                                                                   \
    }

    STAGE(0, 0);
    __syncthreads();   // emits vmcnt(0) drain + barrier

    int swz = l15 & 7;  // read-side row XOR key
    for (int it = 0; it < 16; ++it) {
        int cb = it & 1;
        if (it < 15) STAGE(cb ^ 1, it + 1);   // overlaps with reads+MFMA below

        // A fragments: row = wm*64+mi*16+l15, logical 16B-unit g=lq*2+k at physical g^swz
        bf16x8_t ah[4], al[4];
#pragma unroll
        for (int mi = 0; mi < 4; mi++) {
            int row = wm * 64 + mi * 16 + l15;
            const char* rbase = (const char*)&As[cb][0] + row * 128;
            f32x4_t f0 = *(const f32x4_t*)(rbase + (((lq * 2 + 0) ^ swz) << 4));
            f32x4_t f1 = *(const f32x4_t*)(rbase + (((lq * 2 + 1) ^ swz) << 4));
#pragma unroll
            for (int j = 0; j < 4; j++) {
                ah[mi][j] = bhi(f0[j]);
                al[mi][j] = blo(f0[j]);
                ah[mi][4 + j] = bhi(f1[j]);
                al[mi][4 + j] = blo(f1[j]);
            }
        }
        // B fragments: fragment-linear chunks
        bf16x8_t bh[4], bl[4];
#pragma unroll
        for (int ni = 0; ni < 4; ni++) {
            int c = (wn * 4 + ni) * 64 + lane;
            bh[ni] = *(const bf16x8_t*)(&Bh[cb][0] + (size_t)c * 8);
            bl[ni] = *(const bf16x8_t*)(&Bl[cb][0] + (size_t)c * 8);
        }
#pragma unroll
        for (int mi = 0; mi < 4; mi++)
#pragma unroll
            for (int ni = 0; ni < 4; ni++) {
                acc[mi][ni] = __builtin_amdgcn_mfma_f32_16x16x32_bf16(ah[mi], bh[ni], acc[mi][ni], 0, 0, 0);
                acc[mi][ni] = __builtin_amdgcn_mfma_f32_16x16x32_bf16(al[mi], bh[ni], acc[mi][ni], 0, 0, 0);
                acc[mi][ni] = __builtin_amdgcn_mfma_f32_16x16x32_bf16(ah[mi], bl[ni], acc[mi][ni], 0, 0, 0);
            }
        __syncthreads();  // drains vmcnt (stage done) + lgkmcnt; next iter reads cb^1
    }
#undef STAGE

    // ---- loc gemm: K=64, kc 62/63 zero-padded in wct (compiler-managed loads) ----
    f32x4_t lacc[4][4];
#pragma unroll
    for (int mi = 0; mi < 4; mi++)
#pragma unroll
        for (int ni = 0; ni < 4; ni++) lacc[mi][ni] = (f32x4_t){0.f, 0.f, 0.f, 0.f};
#pragma unroll
    for (int kc0 = 0; kc0 < 64; kc0 += 32) {
        bf16x8_t a2h[4], a2l[4], b2h[4], b2l[4];
#pragma unroll
        for (int mi = 0; mi < 4; mi++) {
            int f = trow0 + wm * 64 + mi * 16 + l15;
            a2h[mi] = *(const bf16x8_t*)(wcthi + (size_t)f * 64 + kc0 + lq * 8);
            a2l[mi] = *(const bf16x8_t*)(wctlo + (size_t)f * 64 + kc0 + lq * 8);
        }
#pragma unroll
        for (int ni = 0; ni < 4; ni++) {
            int a = wn * 64 + ni * 16 + l15;
            size_t off = ((size_t)b * AA + a) * 64 + kc0 + lq * 8;
            b2h[ni] = *(const bf16x8_t*)(zthi + off);
            b2l[ni] = *(const bf16x8_t*)(ztlo + off);
        }
#pragma unroll
        for (int mi = 0; mi < 4; mi++)
#pragma unroll
            for (int ni = 0; ni < 4; ni++) {
                lacc[mi][ni] = __builtin_amdgcn_mfma_f32_16x16x32_bf16(a2h[mi], b2h[ni], lacc[mi][ni], 0, 0, 0);
                lacc[mi][ni] = __builtin_amdgcn_mfma_f32_16x16x32_bf16(a2l[mi], b2h[ni], lacc[mi][ni], 0, 0, 0);
                lacc[mi][ni] = __builtin_amdgcn_mfma_f32_16x16x32_bf16(a2h[mi], b2l[ni], lacc[mi][ni], 0, 0, 0);
            }
    }

    // ---- epilogue ----
    float qv[4], wv[4];
#pragma unroll
    for (int ni = 0; ni < 4; ni++) {
        int a = wn * 64 + ni * 16 + l15;
        qv[ni] = q_ws[b * AA + a];
        wv[ni] = Wv[a];
    }
#pragma unroll
    for (int mi = 0; mi < 4; mi++) {
#pragma unroll
        for (int r = 0; r < 4; r++) {
            int tl = wm * 64 + mi * 16 + lq * 4 + r;
            int t = trow0 + tl;
            float s = 0.f;
#pragma unroll
            for (int ni = 0; ni < 4; ni++) {
                float v = ftanh(acc[mi][ni][r]);
                float loc = ftanh(lacc[mi][ni][r]);
                int a = wn * 64 + ni * 16 + l15;
                v_ws[(size_t)(b * TT + t) * AA + a] = (_Float16)v;
                s += ftanh(qv[ni] + v + loc) * wv[ni];
            }
            s += __shfl_xor(s, 1, 64);
            s += __shfl_xor(s, 2, 64);
            s += __shfl_xor(s, 4, 64);
            s += __shfl_xor(s, 8, 64);
            if (l15 == 0) sc_red[wn * 128 + tl] = s;
        }
    }
    __syncthreads();
    if (tid < 128) score[b * TT + trow0 + tid] = sc_red[tid] + sc_red[128 + tid];
}

// ---------------- K_softmax ----------------
__global__ void k_softmax(const float* __restrict__ score, float* __restrict__ out_align) {
    int b = blockIdx.x, tid = threadIdx.x;
    __shared__ float red[4];
    float s[4];
#pragma unroll
    for (int i = 0; i < 4; i++) s[i] = score[b * TT + tid + i * 256];
    float m = fmaxf(fmaxf(s[0], s[1]), fmaxf(s[2], s[3]));
    for (int off = 32; off; off >>= 1) m = fmaxf(m, __shfl_xor(m, off, 64));
    int wid = tid >> 6;
    if ((tid & 63) == 0) red[wid] = m;
    __syncthreads();
    float M = fmaxf(fmaxf(red[0], red[1]), fmaxf(red[2], red[3]));
    __syncthreads();
    float e[4];
    float sum = 0.f;
#pragma unroll
    for (int i = 0; i < 4; i++) { e[i] = __expf(s[i] - M); sum += e[i]; }
    for (int off = 32; off; off >>= 1) sum += __shfl_xor(sum, off, 64);
    if ((tid & 63) == 0) red[wid] = sum;
    __syncthreads();
    float inv = 1.0f / (red[0] + red[1] + red[2] + red[3]);
#pragma unroll
    for (int i = 0; i < 4; i++) out_align[b * TT + tid + i * 256] = e[i] * inv;
}

// ---------------- K_context: context[b,a] = sum_t align[b,t] * v[b,t,a] (v in f16) ----------------
__global__ void k_context(const float* __restrict__ align, const _Float16* __restrict__ v_ws,
                          float* __restrict__ out_ctx) {
    int b = blockIdx.y, t0 = blockIdx.x * 64, tid = threadIdx.x;
    int a0 = (tid & 31) * 4, tl = tid >> 5;
    __shared__ float sh[8 * 132];
    f32x4_t acc = (f32x4_t){0.f, 0.f, 0.f, 0.f};
    for (int tt = tl; tt < 64; tt += 8) {
        float w = align[b * TT + t0 + tt];
        f16x4_t vv = *(const f16x4_t*)(v_ws + (size_t)(b * TT + t0 + tt) * AA + a0);
        acc[0] += w * (float)vv[0];
        acc[1] += w * (float)vv[1];
        acc[2] += w * (float)vv[2];
        acc[3] += w * (float)vv[3];
    }
    *(f32x4_t*)&sh[tl * 132 + a0] = acc;
    __syncthreads();
    if (tid < 128) {
        float s = 0.f;
#pragma unroll
        for (int j = 0; j < 8; j++) s += sh[j * 132 + tid];
        atomicAdd(out_ctx + b * AA + tid, s);
    }
}

extern "C" void kernel_launch(void* const* d_in, const int* in_sizes, int n_in,
                              void* d_out, int out_size, void* d_ws, size_t ws_size,
                              hipStream_t stream) {
    const float* query = (const float*)d_in[0];
    const float* value = (const float*)d_in[1];
    const float* xcat  = (const float*)d_in[2];
    const float* Wq    = (const float*)d_in[3];
    const float* Wm    = (const float*)d_in[4];
    const float* Wv    = (const float*)d_in[5];
    const float* Wconv = (const float*)d_in[6];
    const float* Wloc  = (const float*)d_in[7];
    float* out = (float*)d_out;

    float* ws = (float*)d_ws;
    float* q_ws  = ws;                       // 8192
    float* sc_ws = q_ws + 8192;              // 65536
    _Float16* v_ws = (_Float16*)(sc_ws + 65536);  // 8388608 halfs = 4194304 floats
    __bf16* pwmhi = (__bf16*)(sc_ws + 65536 + 4194304);
    __bf16* pwmlo = pwmhi + 65536;
    __bf16* wcthi = pwmlo + 65536;
    __bf16* wctlo = wcthi + 65536;
    __bf16* pwlhi = wctlo + 65536;           // 131072
    __bf16* pwllo = pwlhi + 131072;
    __bf16* zthi  = pwllo + 131072;          // 524288
    __bf16* ztlo  = zthi + 524288;

    (void)hipMemsetAsync(out, 0, (size_t)8192 * 4, stream);  // context accumulated via atomics

    k_prep<<<120, 256, 0, stream>>>(Wm, Wconv, Wloc, query, Wq,
                                    pwmhi, pwmlo, wcthi, wctlo, pwlhi, pwllo, q_ws);
    k_zq<<<128, 256, 0, stream>>>(xcat, pwlhi, pwllo, zthi, ztlo);
    k_main<<<512, 256, 0, stream>>>(value, pwmhi, pwmlo, wcthi, wctlo, zthi, ztlo,
                                    q_ws, Wv, v_ws, sc_ws);
    k_softmax<<<BB, 256, 0, stream>>>(sc_ws, out + 8192);
    k_context<<<dim3(16, BB), 256, 0, stream>>>(out + 8192, v_ws, out);
}